// Round 4
// baseline (1029.932 us; speedup 1.0000x reference)
//
#include <hip/hip_runtime.h>
#include <hip/hip_bf16.h>

#define VOCAB  50257
#define KCTX   8
#define EMBED  64
#define HIDDEN 1024
#define BATCH  256

typedef __attribute__((ext_vector_type(8))) short bf16x8;
typedef __attribute__((ext_vector_type(4))) float f32x4;

static __device__ __forceinline__ unsigned short f2bf(float f) {
  union { float f; unsigned u; } un; un.f = f;
  unsigned r = un.u + 0x7FFFu + ((un.u >> 16) & 1u);   // RNE
  return (unsigned short)(r >> 16);
}

static __device__ __forceinline__ short cvbf(float f) {
  union { __hip_bfloat16 h; short s; } u;
  u.h = __float2bfloat16(f);
  return u.s;
}

static __device__ __forceinline__ float silu_f(float x) { return x / (1.f + __expf(-x)); }

// ---------------------------------------------------------------------------
// Kernel 1: early-exit one-hot scan.  One wave per (b,k) row; each iteration
// checks 512 floats (8 coalesced 256B loads), ballot-breaks when found.
// Avg traffic 206 MB (half of full scan).
// ---------------------------------------------------------------------------
__global__ __launch_bounds__(256) void k_scan(const float* __restrict__ ctx,
                                              int* __restrict__ idx,
                                              float* __restrict__ val) {
  int wid = blockIdx.x * 4 + (threadIdx.x >> 6);   // row id, 2048 total
  int lane = threadIdx.x & 63;
  const float* row = ctx + (long)wid * VOCAB;
  int found = 0;
  int base = 0;
  for (; base + 512 <= VOCAB; base += 512) {
    float v[8];
    #pragma unroll
    for (int u = 0; u < 8; ++u) v[u] = row[base + lane + 64 * u];
    bool hit = false;
    #pragma unroll
    for (int u = 0; u < 8; ++u) hit = hit || (v[u] != 0.f);
    if (hit) {
      #pragma unroll
      for (int u = 0; u < 8; ++u)
        if (v[u] != 0.f) { idx[wid] = base + lane + 64 * u; val[wid] = v[u]; }
    }
    if (__any(hit)) { found = 1; break; }
  }
  if (!found) {                                    // tail: 81 floats, guarded
    int i0 = base + lane, i1 = base + 64 + lane;
    float v0 = (i0 < VOCAB) ? row[i0] : 0.f;
    float v1 = (i1 < VOCAB) ? row[i1] : 0.f;
    if (v0 != 0.f) { idx[wid] = i0; val[wid] = v0; }
    if (v1 != 0.f) { idx[wid] = i1; val[wid] = v1; }
  }
}

// ---------------------------------------------------------------------------
// Kernel 2: fused gather + L1 + SiLU + L2 + SiLU -> x2 (bf16).  2 rows/block,
// 128 blocks.  Weights loaded as float4 (16B/lane); x1 lives only in LDS.
// ---------------------------------------------------------------------------
__global__ __launch_bounds__(256) void k_mlp(const int* __restrict__ idx,
                                             const float* __restrict__ val,
                                             const float* __restrict__ embed_w,
                                             const float* __restrict__ W1,
                                             const float* __restrict__ b1,
                                             const float* __restrict__ W2,
                                             const float* __restrict__ b2,
                                             unsigned short* __restrict__ x2) {
  __shared__ float x0[2][512];
  __shared__ float x1[2][1024];
  int r0 = blockIdx.x * 2;
  int t = threadIdx.x;

  // gather embeddings
  for (int e = t; e < 2 * 512; e += 256) {
    int rr = e >> 9, j = e & 511;
    int ks = j >> 6, em = j & 63;
    int bk = (r0 + rr) * KCTX + ks;
    x0[rr][j] = embed_w[idx[bk] * EMBED + em] * val[bk];
  }
  __syncthreads();

  // L1: thread owns cols 4t..4t+3
  {
    float4 acc0 = ((const float4*)b1)[t];
    float4 acc1 = acc0;
    #pragma unroll 4
    for (int j = 0; j < 512; ++j) {
      float4 w = ((const float4*)(W1 + (size_t)j * HIDDEN))[t];
      float xa = x0[0][j], xb = x0[1][j];
      acc0.x = fmaf(xa, w.x, acc0.x); acc0.y = fmaf(xa, w.y, acc0.y);
      acc0.z = fmaf(xa, w.z, acc0.z); acc0.w = fmaf(xa, w.w, acc0.w);
      acc1.x = fmaf(xb, w.x, acc1.x); acc1.y = fmaf(xb, w.y, acc1.y);
      acc1.z = fmaf(xb, w.z, acc1.z); acc1.w = fmaf(xb, w.w, acc1.w);
    }
    float4 s0 = {silu_f(acc0.x), silu_f(acc0.y), silu_f(acc0.z), silu_f(acc0.w)};
    float4 s1 = {silu_f(acc1.x), silu_f(acc1.y), silu_f(acc1.z), silu_f(acc1.w)};
    *(float4*)&x1[0][4 * t] = s0;
    *(float4*)&x1[1][4 * t] = s1;
  }
  __syncthreads();

  // L2
  {
    float4 acc0 = ((const float4*)b2)[t];
    float4 acc1 = acc0;
    #pragma unroll 4
    for (int j = 0; j < 1024; ++j) {
      float4 w = ((const float4*)(W2 + (size_t)j * HIDDEN))[t];
      float xa = x1[0][j], xb = x1[1][j];
      acc0.x = fmaf(xa, w.x, acc0.x); acc0.y = fmaf(xa, w.y, acc0.y);
      acc0.z = fmaf(xa, w.z, acc0.z); acc0.w = fmaf(xa, w.w, acc0.w);
      acc1.x = fmaf(xb, w.x, acc1.x); acc1.y = fmaf(xb, w.y, acc1.y);
      acc1.z = fmaf(xb, w.z, acc1.z); acc1.w = fmaf(xb, w.w, acc1.w);
    }
    ushort4 o0 = {f2bf(silu_f(acc0.x)), f2bf(silu_f(acc0.y)),
                  f2bf(silu_f(acc0.z)), f2bf(silu_f(acc0.w))};
    ushort4 o1 = {f2bf(silu_f(acc1.x)), f2bf(silu_f(acc1.y)),
                  f2bf(silu_f(acc1.z)), f2bf(silu_f(acc1.w))};
    *(ushort4*)(x2 + (size_t)(r0 + 0) * HIDDEN + 4 * t) = o0;
    *(ushort4*)(x2 + (size_t)(r0 + 1) * HIDDEN + 4 * t) = o1;
  }
}

// ---------------------------------------------------------------------------
// Kernel 3: layer 3 via bf16 MFMA, 256 rows x 64 cols per block.
// Fast path: 8 persistent W3 row-pointers stepped once per k-tile; all loads
// use immediate offsets (ni*64 B for B, k0*2 B for A) -> near-zero address VALU.
// Last (ragged) block takes a guarded slow path.
// ---------------------------------------------------------------------------
__global__ __launch_bounds__(256) void k_l3(const short* __restrict__ x2,
                                            const float* __restrict__ W3,
                                            const float* __restrict__ b3,
                                            float* __restrict__ out) {
  int tid = threadIdx.x;
  int wave = tid >> 6, lane = tid & 63;
  int l15 = lane & 15, l4 = lane >> 4;
  int col0 = blockIdx.x * 64;
  int wrow = wave * 64;

  f32x4 acc[4][4];
  #pragma unroll
  for (int mi = 0; mi < 4; ++mi)
    #pragma unroll
    for (int ni = 0; ni < 4; ++ni)
      acc[mi][ni] = (f32x4){0.f, 0.f, 0.f, 0.f};

  const short* aP0 = x2 + (size_t)(wrow +  0 + l15) * HIDDEN + l4 * 8;
  const short* aP1 = x2 + (size_t)(wrow + 16 + l15) * HIDDEN + l4 * 8;
  const short* aP2 = x2 + (size_t)(wrow + 32 + l15) * HIDDEN + l4 * 8;
  const short* aP3 = x2 + (size_t)(wrow + 48 + l15) * HIDDEN + l4 * 8;

  if (col0 + 64 <= VOCAB) {
    // ---- fast path: pointer-stepped, offset-folded loads ----
    const float* p0 = W3 + (size_t)(l4 * 8 + 0) * VOCAB + col0 + l15;
    const float* p1 = W3 + (size_t)(l4 * 8 + 1) * VOCAB + col0 + l15;
    const float* p2 = W3 + (size_t)(l4 * 8 + 2) * VOCAB + col0 + l15;
    const float* p3 = W3 + (size_t)(l4 * 8 + 3) * VOCAB + col0 + l15;
    const float* p4 = W3 + (size_t)(l4 * 8 + 4) * VOCAB + col0 + l15;
    const float* p5 = W3 + (size_t)(l4 * 8 + 5) * VOCAB + col0 + l15;
    const float* p6 = W3 + (size_t)(l4 * 8 + 6) * VOCAB + col0 + l15;
    const float* p7 = W3 + (size_t)(l4 * 8 + 7) * VOCAB + col0 + l15;

    for (int k0 = 0; k0 < HIDDEN; k0 += 32) {
      bf16x8 a0 = *reinterpret_cast<const bf16x8*>(aP0 + k0);
      bf16x8 a1 = *reinterpret_cast<const bf16x8*>(aP1 + k0);
      bf16x8 a2 = *reinterpret_cast<const bf16x8*>(aP2 + k0);
      bf16x8 a3 = *reinterpret_cast<const bf16x8*>(aP3 + k0);
      #pragma unroll
      for (int ni = 0; ni < 4; ++ni) {
        float f0 = p0[ni * 16], f1 = p1[ni * 16], f2 = p2[ni * 16], f3 = p3[ni * 16];
        float f4 = p4[ni * 16], f5 = p5[ni * 16], f6 = p6[ni * 16], f7 = p7[ni * 16];
        bf16x8 bb;
        bb[0] = cvbf(f0); bb[1] = cvbf(f1); bb[2] = cvbf(f2); bb[3] = cvbf(f3);
        bb[4] = cvbf(f4); bb[5] = cvbf(f5); bb[6] = cvbf(f6); bb[7] = cvbf(f7);
        acc[0][ni] = __builtin_amdgcn_mfma_f32_16x16x32_bf16(a0, bb, acc[0][ni], 0, 0, 0);
        acc[1][ni] = __builtin_amdgcn_mfma_f32_16x16x32_bf16(a1, bb, acc[1][ni], 0, 0, 0);
        acc[2][ni] = __builtin_amdgcn_mfma_f32_16x16x32_bf16(a2, bb, acc[2][ni], 0, 0, 0);
        acc[3][ni] = __builtin_amdgcn_mfma_f32_16x16x32_bf16(a3, bb, acc[3][ni], 0, 0, 0);
      }
      p0 += (size_t)32 * VOCAB; p1 += (size_t)32 * VOCAB;
      p2 += (size_t)32 * VOCAB; p3 += (size_t)32 * VOCAB;
      p4 += (size_t)32 * VOCAB; p5 += (size_t)32 * VOCAB;
      p6 += (size_t)32 * VOCAB; p7 += (size_t)32 * VOCAB;
    }
  } else {
    // ---- slow path (last ragged block only) ----
    for (int k0 = 0; k0 < HIDDEN; k0 += 32) {
      int ka = k0 + l4 * 8;
      bf16x8 a0 = *reinterpret_cast<const bf16x8*>(aP0 + k0);
      bf16x8 a1 = *reinterpret_cast<const bf16x8*>(aP1 + k0);
      bf16x8 a2 = *reinterpret_cast<const bf16x8*>(aP2 + k0);
      bf16x8 a3 = *reinterpret_cast<const bf16x8*>(aP3 + k0);
      const float* pBk = W3 + (size_t)ka * VOCAB;
      #pragma unroll
      for (int ni = 0; ni < 4; ++ni) {
        int col = col0 + ni * 16 + l15;
        bool ok = col < VOCAB;
        const float* pB = pBk + (ok ? col : 0);
        bf16x8 bb;
        #pragma unroll
        for (int j = 0; j < 8; ++j) bb[j] = cvbf(ok ? pB[(size_t)j * VOCAB] : 0.f);
        acc[0][ni] = __builtin_amdgcn_mfma_f32_16x16x32_bf16(a0, bb, acc[0][ni], 0, 0, 0);
        acc[1][ni] = __builtin_amdgcn_mfma_f32_16x16x32_bf16(a1, bb, acc[1][ni], 0, 0, 0);
        acc[2][ni] = __builtin_amdgcn_mfma_f32_16x16x32_bf16(a2, bb, acc[2][ni], 0, 0, 0);
        acc[3][ni] = __builtin_amdgcn_mfma_f32_16x16x32_bf16(a3, bb, acc[3][ni], 0, 0, 0);
      }
    }
  }

  #pragma unroll
  for (int ni = 0; ni < 4; ++ni) {
    int col = col0 + ni * 16 + l15;
    if (col < VOCAB) {
      float bb = b3[col];
      #pragma unroll
      for (int mi = 0; mi < 4; ++mi) {
        #pragma unroll
        for (int r = 0; r < 4; ++r) {
          int row = wrow + mi * 16 + l4 * 4 + r;
          out[(size_t)row * VOCAB + col] = acc[mi][ni][r] + bb;
        }
      }
    }
  }
}

// ---------------------------------------------------------------------------
extern "C" void kernel_launch(void* const* d_in, const int* in_sizes, int n_in,
                              void* d_out, int out_size, void* d_ws, size_t ws_size,
                              hipStream_t stream) {
  const float* ctx     = (const float*)d_in[0];
  const float* embed_w = (const float*)d_in[1];
  const float* W1      = (const float*)d_in[2];
  const float* b1      = (const float*)d_in[3];
  const float* W2      = (const float*)d_in[4];
  const float* b2      = (const float*)d_in[5];
  const float* W3      = (const float*)d_in[6];
  const float* b3      = (const float*)d_in[7];
  float* out = (float*)d_out;

  char* w = (char*)d_ws;
  int*            idx = (int*)w;                         // 8 KB
  float*          val = (float*)(w + 8192);              // 8 KB
  unsigned short* x2  = (unsigned short*)(w + 16384);    // 512 KB

  k_scan<<<BATCH * KCTX / 4, 256, 0, stream>>>(ctx, idx, val);
  k_mlp<<<BATCH / 2, 256, 0, stream>>>(idx, val, embed_w, W1, b1, W2, b2, x2);
  k_l3<<<(VOCAB + 63) / 64, 256, 0, stream>>>((const short*)x2, W3, b3, out);
}

// Round 5
// 909.770 us; speedup vs baseline: 1.1321x; 1.1321x over previous
//
#include <hip/hip_runtime.h>
#include <hip/hip_bf16.h>

#define VOCAB  50257
#define KCTX   8
#define EMBED  64
#define HIDDEN 1024
#define BATCH  256

typedef __attribute__((ext_vector_type(8))) short bf16x8;
typedef __attribute__((ext_vector_type(4))) float f32x4;

static __device__ __forceinline__ unsigned short f2bf(float f) {
  union { float f; unsigned u; } un; un.f = f;
  unsigned r = un.u + 0x7FFFu + ((un.u >> 16) & 1u);   // RNE
  return (unsigned short)(r >> 16);
}

static __device__ __forceinline__ short cvbf(float f) {
  union { __hip_bfloat16 h; short s; } u;
  u.h = __float2bfloat16(f);
  return u.s;
}

static __device__ __forceinline__ float silu_f(float x) { return x / (1.f + __expf(-x)); }

// ---------------------------------------------------------------------------
// Kernel 1: early-exit one-hot scan.  One wave per (b,k) row; 8KB chunks
// (32 scalar dword loads per lane) -> <=25 serial latency round-trips per row.
// NOTE: row stride 50257 floats is ODD -> per-row float4 would be misaligned;
// scalar dword loads only.
// ---------------------------------------------------------------------------
__global__ __launch_bounds__(256) void k_scan(const float* __restrict__ ctx,
                                              int* __restrict__ idx,
                                              float* __restrict__ val) {
  int wid = blockIdx.x * 4 + (threadIdx.x >> 6);   // row id, 2048 total
  int lane = threadIdx.x & 63;
  const float* row = ctx + (size_t)wid * VOCAB;
  bool found = false;
  int base = 0;
  for (; base + 2048 <= VOCAB; base += 2048) {
    float v[32];
    #pragma unroll
    for (int u = 0; u < 32; ++u) v[u] = row[base + lane + 64 * u];
    bool hit = false;
    #pragma unroll
    for (int u = 0; u < 32; ++u) hit = hit || (v[u] != 0.f);
    if (hit) {
      #pragma unroll
      for (int u = 0; u < 32; ++u)
        if (v[u] != 0.f) { idx[wid] = base + lane + 64 * u; val[wid] = v[u]; }
    }
    if (__any(hit)) { found = true; break; }
  }
  if (!found) {                                    // tail: 1105 elems, guarded
    #pragma unroll
    for (int u = 0; u < 18; ++u) {
      int i = base + lane + 64 * u;
      float v = (i < VOCAB) ? row[i] : 0.f;
      if (v != 0.f) { idx[wid] = i; val[wid] = v; }
    }
  }
}

// ---------------------------------------------------------------------------
// Kernel 2: fused gather + L1 + SiLU + L2 + SiLU -> x2 (bf16).
// 1 row/block, 256 blocks (all CUs busy).  float4 weight loads, unroll 8.
// ---------------------------------------------------------------------------
__global__ __launch_bounds__(256) void k_mlp(const int* __restrict__ idx,
                                             const float* __restrict__ val,
                                             const float* __restrict__ embed_w,
                                             const float* __restrict__ W1,
                                             const float* __restrict__ b1,
                                             const float* __restrict__ W2,
                                             const float* __restrict__ b2,
                                             unsigned short* __restrict__ x2) {
  __shared__ float x0[512];
  __shared__ float x1[1024];
  int r = blockIdx.x;
  int t = threadIdx.x;

  for (int e = t; e < 512; e += 256) {
    int ks = e >> 6, em = e & 63;
    int bk = r * KCTX + ks;
    x0[e] = embed_w[idx[bk] * EMBED + em] * val[bk];
  }
  __syncthreads();

  {
    float4 acc = ((const float4*)b1)[t];
    #pragma unroll 8
    for (int j = 0; j < 512; ++j) {
      float4 w = ((const float4*)(W1 + (size_t)j * HIDDEN))[t];
      float xa = x0[j];
      acc.x = fmaf(xa, w.x, acc.x); acc.y = fmaf(xa, w.y, acc.y);
      acc.z = fmaf(xa, w.z, acc.z); acc.w = fmaf(xa, w.w, acc.w);
    }
    float4 s = {silu_f(acc.x), silu_f(acc.y), silu_f(acc.z), silu_f(acc.w)};
    *(float4*)&x1[4 * t] = s;
  }
  __syncthreads();

  {
    float4 acc = ((const float4*)b2)[t];
    #pragma unroll 8
    for (int j = 0; j < 1024; ++j) {
      float4 w = ((const float4*)(W2 + (size_t)j * HIDDEN))[t];
      float xa = x1[j];
      acc.x = fmaf(xa, w.x, acc.x); acc.y = fmaf(xa, w.y, acc.y);
      acc.z = fmaf(xa, w.z, acc.z); acc.w = fmaf(xa, w.w, acc.w);
    }
    ushort4 o = {f2bf(silu_f(acc.x)), f2bf(silu_f(acc.y)),
                 f2bf(silu_f(acc.z)), f2bf(silu_f(acc.w))};
    *(ushort4*)(x2 + (size_t)r * HIDDEN + 4 * t) = o;
  }
}

// ---------------------------------------------------------------------------
// Kernel 3: layer 3 via bf16 MFMA, 256 rows x 64 cols per block.
// W3 k-tile (32x64 f32) staged to LDS, double-buffered, XOR-swizzled
// (col ^ ((row>>3&1)<<4)) so the 32 ds_read_b32 B-frag reads are 2-way/free.
// Staging uses scalar dword loads (W3 row stride 50257 is odd -> no float4).
// __launch_bounds__(256,4) caps VGPR at 128 -> 4 waves/SIMD.
// ---------------------------------------------------------------------------
__global__ __launch_bounds__(256, 4) void k_l3(const short* __restrict__ x2,
                                               const float* __restrict__ W3,
                                               const float* __restrict__ b3,
                                               float* __restrict__ out) {
  __shared__ float bs[2][32][68];                  // 17.4 KB, pad 68: bank = 4*row + col
  int tid = threadIdx.x;
  int wave = tid >> 6, lane = tid & 63;
  int l15 = lane & 15, l4 = lane >> 4;
  int col0 = blockIdx.x * 64;
  int wrow = wave * 64;

  f32x4 acc[4][4];
  #pragma unroll
  for (int mi = 0; mi < 4; ++mi)
    #pragma unroll
    for (int ni = 0; ni < 4; ++ni)
      acc[mi][ni] = (f32x4){0.f, 0.f, 0.f, 0.f};

  const short* aP0 = x2 + (size_t)(wrow +  0 + l15) * HIDDEN + l4 * 8;
  const short* aP1 = x2 + (size_t)(wrow + 16 + l15) * HIDDEN + l4 * 8;
  const short* aP2 = x2 + (size_t)(wrow + 32 + l15) * HIDDEN + l4 * 8;
  const short* aP3 = x2 + (size_t)(wrow + 48 + l15) * HIDDEN + l4 * 8;

  if (col0 + 64 <= VOCAB) {
    // ---- fast path: LDS-staged, double-buffered ----
    int sr = tid >> 3;                             // staging row 0..31
    int sc = (tid & 7) * 8;                        // staging col 0..56
    int scx = sc ^ (((sr >> 3) & 1) << 4);         // swizzled col
    const float* gs = W3 + (size_t)sr * VOCAB + col0 + sc;

    {                                              // prologue: stage k-tile 0
      float f[8];
      #pragma unroll
      for (int u = 0; u < 8; ++u) f[u] = gs[u];
      float4 q0 = {f[0], f[1], f[2], f[3]};
      float4 q1 = {f[4], f[5], f[6], f[7]};
      *(float4*)&bs[0][sr][scx] = q0;
      *(float4*)&bs[0][sr][scx + 4] = q1;
    }
    __syncthreads();

    int swk = (l4 & 1) << 4;                       // reader swizzle key (row>>3 = l4)

    for (int it = 0; it < 32; ++it) {
      int cur = it & 1;
      // issue next-tile global loads early (T14: issue-early / write-late)
      float f[8];
      bool more = (it + 1) < 32;
      if (more) {
        const float* g2 = gs + (size_t)(it + 1) * 32 * VOCAB;
        #pragma unroll
        for (int u = 0; u < 8; ++u) f[u] = g2[u];
      }
      // A fragments (x2 is L2-resident)
      int k0 = it * 32;
      bf16x8 a0 = *reinterpret_cast<const bf16x8*>(aP0 + k0);
      bf16x8 a1 = *reinterpret_cast<const bf16x8*>(aP1 + k0);
      bf16x8 a2 = *reinterpret_cast<const bf16x8*>(aP2 + k0);
      bf16x8 a3 = *reinterpret_cast<const bf16x8*>(aP3 + k0);
      // B fragments from LDS + MFMA
      #pragma unroll
      for (int ni = 0; ni < 4; ++ni) {
        const float* bp = &bs[cur][l4 * 8][((16 * ni) ^ swk) + l15];
        bf16x8 bb;
        #pragma unroll
        for (int j = 0; j < 8; ++j) bb[j] = cvbf(bp[j * 68]);
        acc[0][ni] = __builtin_amdgcn_mfma_f32_16x16x32_bf16(a0, bb, acc[0][ni], 0, 0, 0);
        acc[1][ni] = __builtin_amdgcn_mfma_f32_16x16x32_bf16(a1, bb, acc[1][ni], 0, 0, 0);
        acc[2][ni] = __builtin_amdgcn_mfma_f32_16x16x32_bf16(a2, bb, acc[2][ni], 0, 0, 0);
        acc[3][ni] = __builtin_amdgcn_mfma_f32_16x16x32_bf16(a3, bb, acc[3][ni], 0, 0, 0);
      }
      // write next tile to the other buffer, then one barrier per k-step
      if (more) {
        float4 q0 = {f[0], f[1], f[2], f[3]};
        float4 q1 = {f[4], f[5], f[6], f[7]};
        *(float4*)&bs[cur ^ 1][sr][scx] = q0;
        *(float4*)&bs[cur ^ 1][sr][scx + 4] = q1;
      }
      __syncthreads();
    }
  } else {
    // ---- slow path (last ragged block only): direct guarded loads ----
    for (int k0 = 0; k0 < HIDDEN; k0 += 32) {
      int ka = k0 + l4 * 8;
      bf16x8 a0 = *reinterpret_cast<const bf16x8*>(aP0 + k0);
      bf16x8 a1 = *reinterpret_cast<const bf16x8*>(aP1 + k0);
      bf16x8 a2 = *reinterpret_cast<const bf16x8*>(aP2 + k0);
      bf16x8 a3 = *reinterpret_cast<const bf16x8*>(aP3 + k0);
      const float* pBk = W3 + (size_t)ka * VOCAB;
      #pragma unroll
      for (int ni = 0; ni < 4; ++ni) {
        int col = col0 + ni * 16 + l15;
        bool ok = col < VOCAB;
        const float* pB = pBk + (ok ? col : 0);
        bf16x8 bb;
        #pragma unroll
        for (int j = 0; j < 8; ++j) bb[j] = cvbf(ok ? pB[(size_t)j * VOCAB] : 0.f);
        acc[0][ni] = __builtin_amdgcn_mfma_f32_16x16x32_bf16(a0, bb, acc[0][ni], 0, 0, 0);
        acc[1][ni] = __builtin_amdgcn_mfma_f32_16x16x32_bf16(a1, bb, acc[1][ni], 0, 0, 0);
        acc[2][ni] = __builtin_amdgcn_mfma_f32_16x16x32_bf16(a2, bb, acc[2][ni], 0, 0, 0);
        acc[3][ni] = __builtin_amdgcn_mfma_f32_16x16x32_bf16(a3, bb, acc[3][ni], 0, 0, 0);
      }
    }
  }

  #pragma unroll
  for (int ni = 0; ni < 4; ++ni) {
    int col = col0 + ni * 16 + l15;
    if (col < VOCAB) {
      float bb = b3[col];
      #pragma unroll
      for (int mi = 0; mi < 4; ++mi) {
        #pragma unroll
        for (int r = 0; r < 4; ++r) {
          int row = wrow + mi * 16 + l4 * 4 + r;
          out[(size_t)row * VOCAB + col] = acc[mi][ni][r] + bb;
        }
      }
    }
  }
}

// ---------------------------------------------------------------------------
extern "C" void kernel_launch(void* const* d_in, const int* in_sizes, int n_in,
                              void* d_out, int out_size, void* d_ws, size_t ws_size,
                              hipStream_t stream) {
  const float* ctx     = (const float*)d_in[0];
  const float* embed_w = (const float*)d_in[1];
  const float* W1      = (const float*)d_in[2];
  const float* b1      = (const float*)d_in[3];
  const float* W2      = (const float*)d_in[4];
  const float* b2      = (const float*)d_in[5];
  const float* W3      = (const float*)d_in[6];
  const float* b3      = (const float*)d_in[7];
  float* out = (float*)d_out;

  char* w = (char*)d_ws;
  int*            idx = (int*)w;                         // 8 KB
  float*          val = (float*)(w + 8192);              // 8 KB
  unsigned short* x2  = (unsigned short*)(w + 16384);    // 512 KB

  k_scan<<<BATCH * KCTX / 4, 256, 0, stream>>>(ctx, idx, val);
  k_mlp<<<BATCH, 256, 0, stream>>>(idx, val, embed_w, W1, b1, W2, b2, x2);
  k_l3<<<(VOCAB + 63) / 64, 256, 0, stream>>>((const short*)x2, W3, b3, out);
}